// Round 1
// baseline (3012.049 us; speedup 1.0000x reference)
//
#include <hip/hip_runtime.h>
#include <math.h>

#define NN 50000
#define EE 800000
#define DIN 128

// ---------------- degree count ----------------
__global__ void count_kernel(const int* __restrict__ dst, float* __restrict__ cnt, int E) {
    int e = blockIdx.x * blockDim.x + threadIdx.x;
    if (e < E) atomicAdd(&cnt[dst[e]], 1.0f);
}

// ---------------- scatter-add of source features into agg[dst] ----------------
// 32 threads per edge, one float4 each (128 floats per row).
__global__ void scatter_kernel(const float4* __restrict__ x4, const int* __restrict__ src,
                               const int* __restrict__ dst, float* __restrict__ agg, int E) {
    long long tid = (long long)blockIdx.x * blockDim.x + threadIdx.x;
    int e = (int)(tid >> 5);
    int c = (int)(tid & 31);
    if (e >= E) return;
    int s = src[e];
    int d = dst[e];
    float4 v = x4[(size_t)s * 32 + c];
    float* a = agg + (size_t)d * DIN + c * 4;
    atomicAdd(a + 0, v.x);
    atomicAdd(a + 1, v.y);
    atomicAdd(a + 2, v.z);
    atomicAdd(a + 3, v.w);
}

// ---------------- fused SAGE layer: out = normalize(mean @ Wl + b + x @ Wr) ----------------
// blockDim.x == DOUT, NPB nodes per block. DIN fixed at 128.
template <int DOUT, int NPB>
__global__ void layer_kernel(const float* __restrict__ xin, const float* __restrict__ agg,
                             const float* __restrict__ cnt,
                             const float* __restrict__ wl, const float* __restrict__ bias,
                             const float* __restrict__ wr, float* __restrict__ out, int n) {
    __shared__ float xs[NPB][DIN];
    __shared__ float ms[NPB][DIN];
    __shared__ float outs[NPB][DOUT + 1];   // +1 pad: kill bank aliasing in norm pass
    __shared__ float rn[NPB];

    const int j = threadIdx.x;
    const int node0 = blockIdx.x * NPB;
    const int VEC = DIN / 4;  // 32 float4 per row

    // cooperative load of x rows and mean rows (agg/cnt) into LDS
    for (int idx = j; idx < NPB * VEC; idx += DOUT) {
        int row = idx / VEC;
        int c = idx % VEC;
        int node = node0 + row;
        if (node < n) {
            float4 xv = ((const float4*)xin)[(size_t)node * VEC + c];
            float4 av = ((const float4*)agg)[(size_t)node * VEC + c];
            float ic = 1.0f / fmaxf(cnt[node], 1.0f);
            ((float4*)xs[row])[c] = xv;
            float4 mv;
            mv.x = av.x * ic; mv.y = av.y * ic; mv.z = av.z * ic; mv.w = av.w * ic;
            ((float4*)ms[row])[c] = mv;
        }
    }
    __syncthreads();

    float acc[NPB];
    const float bj = bias[j];
#pragma unroll
    for (int nI = 0; nI < NPB; nI++) acc[nI] = bj;

    for (int k = 0; k < DIN; k++) {
        float a = wl[k * DOUT + j];   // coalesced across j, L2-resident
        float b = wr[k * DOUT + j];
#pragma unroll
        for (int nI = 0; nI < NPB; nI++)
            acc[nI] += ms[nI][k] * a + xs[nI][k] * b;  // LDS broadcast reads
    }

#pragma unroll
    for (int nI = 0; nI < NPB; nI++) outs[nI][j] = acc[nI];
    __syncthreads();

    if (j < NPB) {
        float s = 0.0f;
        for (int q = 0; q < DOUT; q++) {
            float v = outs[j][q];
            s += v * v;
        }
        float nrm = fmaxf(sqrtf(s), 1e-12f);
        rn[j] = 1.0f / nrm;
    }
    __syncthreads();

#pragma unroll
    for (int nI = 0; nI < NPB; nI++) {
        int node = node0 + nI;
        if (node < n) out[(size_t)node * DOUT + j] = outs[nI][j] * rn[nI];
    }
}

extern "C" void kernel_launch(void* const* d_in, const int* in_sizes, int n_in,
                              void* d_out, int out_size, void* d_ws, size_t ws_size,
                              hipStream_t stream) {
    const float* x   = (const float*)d_in[0];
    const int*   ei  = (const int*)d_in[1];   // [2, E] int32 (row 0 = src, row 1 = dst)
    const float* w1l = (const float*)d_in[2];
    const float* b1  = (const float*)d_in[3];
    const float* w1r = (const float*)d_in[4];
    const float* w2l = (const float*)d_in[5];
    const float* b2  = (const float*)d_in[6];
    const float* w2r = (const float*)d_in[7];
    float* out = (float*)d_out;

    const int* src = ei;
    const int* dst = ei + EE;

    char* ws = (char*)d_ws;
    const size_t aggBytes = (size_t)NN * DIN * sizeof(float);      // 25.6 MB
    const size_t cntBytes = ((size_t)NN * sizeof(float) + 255) & ~(size_t)255;
    float* agg = (float*)ws;
    float* cnt = (float*)(ws + aggBytes);
    float* h1  = (float*)(ws + aggBytes + cntBytes);               // N*128 f32

    // ---- layer 1 ----
    hipMemsetAsync(agg, 0, aggBytes, stream);
    hipMemsetAsync(cnt, 0, (size_t)NN * sizeof(float), stream);
    count_kernel<<<(EE + 255) / 256, 256, 0, stream>>>(dst, cnt, EE);
    {
        long long tot = (long long)EE * 32;
        scatter_kernel<<<(int)((tot + 255) / 256), 256, 0, stream>>>((const float4*)x, src, dst, agg, EE);
    }
    layer_kernel<128, 8><<<NN / 8, 128, 0, stream>>>(x, agg, cnt, w1l, b1, w1r, h1, NN);

    // ---- layer 2 ----
    hipMemsetAsync(agg, 0, aggBytes, stream);
    {
        long long tot = (long long)EE * 32;
        scatter_kernel<<<(int)((tot + 255) / 256), 256, 0, stream>>>((const float4*)h1, src, dst, agg, EE);
    }
    layer_kernel<64, 8><<<NN / 8, 64, 0, stream>>>(h1, agg, cnt, w2l, b2, w2r, out, NN);
}

// Round 2
// 614.098 us; speedup vs baseline: 4.9048x; 4.9048x over previous
//
#include <hip/hip_runtime.h>
#include <math.h>

#define NN 50000
#define EE 800000
#define DIN 128

// ---------------- degree count (int atomics) ----------------
__global__ void count_kernel(const int* __restrict__ dst, int* __restrict__ deg, int E) {
    int e = blockIdx.x * blockDim.x + threadIdx.x;
    if (e < E) atomicAdd(&deg[dst[e]], 1);
}

// ---------------- exclusive scan of deg -> rowoff (single block, 1024 thr) ----------------
__global__ void scan_kernel(const int* __restrict__ deg, int* __restrict__ rowoff, int n) {
    __shared__ int sums[1024];
    const int t = threadIdx.x;
    const int per = (n + 1023) / 1024;
    int lo = t * per;
    int hi = lo + per; if (hi > n) hi = n; if (lo > n) lo = n;
    int s = 0;
    for (int i = lo; i < hi; i++) s += deg[i];
    sums[t] = s;
    __syncthreads();
    for (int ofs = 1; ofs < 1024; ofs <<= 1) {
        int v = sums[t];
        int add = (t >= ofs) ? sums[t - ofs] : 0;
        __syncthreads();
        sums[t] = v + add;
        __syncthreads();
    }
    int run = (t == 0) ? 0 : sums[t - 1];
    for (int i = lo; i < hi; i++) { rowoff[i] = run; run += deg[i]; }
    if (t == 1023) rowoff[n] = sums[1023];
}

// ---------------- cursor init ----------------
__global__ void cursor_init_kernel(const int* __restrict__ rowoff, int* __restrict__ cursor, int n) {
    int i = blockIdx.x * blockDim.x + threadIdx.x;
    if (i < n) cursor[i] = rowoff[i];
}

// ---------------- CSR fill: csr[rowoff[d] + k] = src of k-th edge into d ----------------
__global__ void fill_kernel(const int* __restrict__ src, const int* __restrict__ dst,
                            int* __restrict__ cursor, int* __restrict__ csr, int E) {
    int e = blockIdx.x * blockDim.x + threadIdx.x;
    if (e < E) {
        int d = dst[e];
        int p = atomicAdd(&cursor[d], 1);
        csr[p] = src[e];
    }
}

// ---------------- fused SAGE layer: gather-mean + (mean@Wl + b + x@Wr) + L2norm ----------------
// blockDim = 128. NPB nodes per block. DIN fixed = 128.
template <int DOUT, int NPB>
__global__ __launch_bounds__(128) void layer_kernel(
        const float* __restrict__ xin, const int* __restrict__ rowoff, const int* __restrict__ csr,
        const float* __restrict__ wl, const float* __restrict__ bias, const float* __restrict__ wr,
        float* __restrict__ out, int n) {
    __shared__ float2 zs[NPB][DIN];        // {mean, x} interleaved -> ds_read_b64 in matmul
    __shared__ float outs[NPB][DOUT + 1];  // +1 pad for norm pass
    __shared__ float rn[NPB];

    const int j = threadIdx.x;             // 0..127 (feature column in gather phase)
    const int node0 = blockIdx.x * NPB;
    constexpr int GROUPS = 128 / DOUT;
    constexpr int MY = NPB / GROUPS;
    const int col = j % DOUT;
    const int grp = j / DOUT;

    // ---- gather phase: thread j accumulates column j over each node's neighbors ----
    for (int nI = 0; nI < NPB; nI++) {
        int node = node0 + nI;
        if (node >= n) { zs[nI][j] = make_float2(0.f, 0.f); continue; }
        int off = rowoff[node], end = rowoff[node + 1];
        float x_j = xin[(size_t)node * DIN + j];
        float m0 = 0.f, m1 = 0.f;
        int k = off;
        for (; k + 2 <= end; k += 2) {
            int s0 = csr[k], s1 = csr[k + 1];
            m0 += xin[(size_t)s0 * DIN + j];
            m1 += xin[(size_t)s1 * DIN + j];
        }
        if (k < end) m0 += xin[(size_t)csr[k] * DIN + j];
        float ic = 1.0f / fmaxf((float)(end - off), 1.0f);
        zs[nI][j] = make_float2((m0 + m1) * ic, x_j);
    }
    __syncthreads();

    // ---- matmul phase: thread (grp,col) computes out col for MY nodes ----
    float acc[MY];
    const float bj = bias[col];
#pragma unroll
    for (int nI = 0; nI < MY; nI++) acc[nI] = bj;

    for (int k = 0; k < DIN; k++) {
        float a = wl[k * DOUT + col];
        float b = wr[k * DOUT + col];
#pragma unroll
        for (int nI = 0; nI < MY; nI++) {
            float2 z = zs[grp * MY + nI][k];   // broadcast within wave
            acc[nI] += z.x * a + z.y * b;
        }
    }

#pragma unroll
    for (int nI = 0; nI < MY; nI++) outs[grp * MY + nI][col] = acc[nI];
    __syncthreads();

    // ---- L2 norm ----
    if (j < NPB) {
        float s = 0.f;
        for (int q = 0; q < DOUT; q++) { float v = outs[j][q]; s += v * v; }
        rn[j] = 1.0f / fmaxf(sqrtf(s), 1e-12f);
    }
    __syncthreads();

#pragma unroll
    for (int nI = 0; nI < MY; nI++) {
        int node = node0 + grp * MY + nI;
        if (node < n) out[(size_t)node * DOUT + col] = outs[grp * MY + nI][col] * rn[grp * MY + nI];
    }
}

extern "C" void kernel_launch(void* const* d_in, const int* in_sizes, int n_in,
                              void* d_out, int out_size, void* d_ws, size_t ws_size,
                              hipStream_t stream) {
    const float* x   = (const float*)d_in[0];
    const int*   ei  = (const int*)d_in[1];   // [2, E] int32
    const float* w1l = (const float*)d_in[2];
    const float* b1  = (const float*)d_in[3];
    const float* w1r = (const float*)d_in[4];
    const float* w2l = (const float*)d_in[5];
    const float* b2  = (const float*)d_in[6];
    const float* w2r = (const float*)d_in[7];
    float* out = (float*)d_out;

    const int* src = ei;
    const int* dst = ei + EE;

    // workspace layout (all 256B aligned)
    char* ws = (char*)d_ws;
    auto align = [](size_t v) { return (v + 255) & ~(size_t)255; };
    int*   deg    = (int*)ws;                 size_t o = align((size_t)NN * 4);
    int*   rowoff = (int*)(ws + o);           o += align((size_t)(NN + 1) * 4);
    int*   cursor = (int*)(ws + o);           o += align((size_t)NN * 4);
    int*   csr    = (int*)(ws + o);           o += align((size_t)EE * 4);
    float* h1     = (float*)(ws + o);         // N*128 f32

    // ---- build CSR ----
    hipMemsetAsync(deg, 0, (size_t)NN * 4, stream);
    count_kernel<<<(EE + 255) / 256, 256, 0, stream>>>(dst, deg, EE);
    scan_kernel<<<1, 1024, 0, stream>>>(deg, rowoff, NN);
    cursor_init_kernel<<<(NN + 255) / 256, 256, 0, stream>>>(rowoff, cursor, NN);
    fill_kernel<<<(EE + 255) / 256, 256, 0, stream>>>(src, dst, cursor, csr, EE);

    // ---- layer 1: 128 -> 128 ----
    layer_kernel<128, 16><<<(NN + 15) / 16, 128, 0, stream>>>(x, rowoff, csr, w1l, b1, w1r, h1, NN);
    // ---- layer 2: 128 -> 64 ----
    layer_kernel<64, 16><<<(NN + 15) / 16, 128, 0, stream>>>(h1, rowoff, csr, w2l, b2, w2r, out, NN);
}

// Round 3
// 418.230 us; speedup vs baseline: 7.2019x; 1.4683x over previous
//
#include <hip/hip_runtime.h>
#include <math.h>

#define NN 50000
#define EE 800000

// ---------------- CSR build ----------------
__global__ void count_kernel(const int* __restrict__ dst, int* __restrict__ deg, int E) {
    int e = blockIdx.x * blockDim.x + threadIdx.x;
    if (e < E) atomicAdd(&deg[dst[e]], 1);
}

__global__ void scan_kernel(const int* __restrict__ deg, int* __restrict__ rowoff, int n) {
    __shared__ int sums[1024];
    const int t = threadIdx.x;
    const int per = (n + 1023) / 1024;
    int lo = t * per;
    int hi = lo + per; if (hi > n) hi = n; if (lo > n) lo = n;
    int s = 0;
    for (int i = lo; i < hi; i++) s += deg[i];
    sums[t] = s;
    __syncthreads();
    for (int ofs = 1; ofs < 1024; ofs <<= 1) {
        int v = sums[t];
        int add = (t >= ofs) ? sums[t - ofs] : 0;
        __syncthreads();
        sums[t] = v + add;
        __syncthreads();
    }
    int run = (t == 0) ? 0 : sums[t - 1];
    for (int i = lo; i < hi; i++) { rowoff[i] = run; run += deg[i]; }
    if (t == 1023) rowoff[n] = sums[1023];
}

__global__ void cursor_init_kernel(const int* __restrict__ rowoff, int* __restrict__ cursor, int n) {
    int i = blockIdx.x * blockDim.x + threadIdx.x;
    if (i < n) cursor[i] = rowoff[i];
}

__global__ void fill_kernel(const int* __restrict__ src, const int* __restrict__ dst,
                            int* __restrict__ cursor, int* __restrict__ csr, int E) {
    int e = blockIdx.x * blockDim.x + threadIdx.x;
    if (e < E) {
        int d = dst[e];
        int p = atomicAdd(&cursor[d], 1);
        csr[p] = src[e];
    }
}

// ---------------- dense transform: out[n][CO] = x[n] @ [Wl | Wr], bias on right half ----
// K=128. CO=256 (layer1) or 128 (layer2). Wl,Wr row-major [K][CO/2].
template <int CO>
__global__ __launch_bounds__(256) void transform_kernel(
        const float* __restrict__ x, const float* __restrict__ wl,
        const float* __restrict__ wr, const float* __restrict__ bias,
        float* __restrict__ out, int n) {
    constexpr int K = 128;
    constexpr int NPB = 64;
    constexpr int CG = CO / 4;        // col groups of 4 cols
    constexpr int NG = 256 / CG;      // node groups
    constexpr int MY = NPB / NG;      // nodes per thread (16 or 8)
    constexpr int HALF = CO / 2;
    __shared__ float xs[NPB][K + 4];  // pad 4: row stride 528B (16B aligned), conflict-light

    const int t = threadIdx.x;
    const int node0 = blockIdx.x * NPB;

    // stage x rows (64 rows x 32 float4), coalesced
    for (int e = t; e < NPB * 32; e += 256) {
        int c4 = e & 31, nd = e >> 5;
        int node = node0 + nd;
        float4 v = (node < n) ? ((const float4*)x)[(size_t)node * 32 + c4]
                              : make_float4(0.f, 0.f, 0.f, 0.f);
        *(float4*)&xs[nd][c4 * 4] = v;
    }
    __syncthreads();

    const int cg = t % CG;
    const int ng = t / CG;
    const int c0 = cg * 4;
    const bool right = (c0 >= HALF);
    const float* wsel = right ? wr : wl;
    const int cb = right ? (c0 - HALF) : c0;

    float acc[MY][4];
#pragma unroll
    for (int m = 0; m < MY; m++)
#pragma unroll
        for (int q = 0; q < 4; q++)
            acc[m][q] = right ? bias[cb + q] : 0.f;

    for (int k = 0; k < K; k++) {
        float4 w4 = *(const float4*)(wsel + (size_t)k * HALF + cb);
#pragma unroll
        for (int m = 0; m < MY; m++) {
            float xv = xs[ng * MY + m][k];   // whole-wave broadcast
            acc[m][0] += xv * w4.x;
            acc[m][1] += xv * w4.y;
            acc[m][2] += xv * w4.z;
            acc[m][3] += xv * w4.w;
        }
    }

#pragma unroll
    for (int m = 0; m < MY; m++) {
        int node = node0 + ng * MY + m;
        if (node < n)
            *(float4*)&out[(size_t)node * CO + c0] =
                make_float4(acc[m][0], acc[m][1], acc[m][2], acc[m][3]);
    }
}

// ---------------- gather + mean + add-root + L2norm ----------------
// yr rows: [y(0..D-1) | r(D..2D-1)], stride 2D. One wave per node.
template <int D>
__global__ __launch_bounds__(256) void gather_norm_kernel(
        const float* __restrict__ yr, const int* __restrict__ rowoff,
        const int* __restrict__ csr, float* __restrict__ out, int n) {
    const int wave = threadIdx.x >> 6;
    const int lane = threadIdx.x & 63;
    const int node = blockIdx.x * 4 + wave;
    if (node >= n) return;

    const int off = rowoff[node];
    const int end = rowoff[node + 1];
    const int deg = end - off;

    if (D == 128) {
        float2 acc = make_float2(0.f, 0.f);
        for (int k0 = 0; k0 < deg; k0 += 8) {
            int idx[8];
#pragma unroll
            for (int i = 0; i < 8; i++) {
                int kk = off + k0 + i;
                idx[i] = csr[kk < end ? kk : end - 1];
            }
            float2 v[8];
#pragma unroll
            for (int i = 0; i < 8; i++)
                v[i] = *(const float2*)(yr + (size_t)idx[i] * 256 + 2 * lane);
#pragma unroll
            for (int i = 0; i < 8; i++)
                if (k0 + i < deg) { acc.x += v[i].x; acc.y += v[i].y; }
        }
        float im = 1.0f / fmaxf((float)deg, 1.0f);
        float2 r = *(const float2*)(yr + (size_t)node * 256 + 128 + 2 * lane);
        float2 v = make_float2(acc.x * im + r.x, acc.y * im + r.y);
        float s = v.x * v.x + v.y * v.y;
#pragma unroll
        for (int m = 32; m >= 1; m >>= 1) s += __shfl_xor(s, m, 64);
        float rn = 1.0f / fmaxf(sqrtf(s), 1e-12f);
        *(float2*)&out[(size_t)node * 128 + 2 * lane] = make_float2(v.x * rn, v.y * rn);
    } else {
        float acc = 0.f;
        for (int k0 = 0; k0 < deg; k0 += 8) {
            int idx[8];
#pragma unroll
            for (int i = 0; i < 8; i++) {
                int kk = off + k0 + i;
                idx[i] = csr[kk < end ? kk : end - 1];
            }
            float v[8];
#pragma unroll
            for (int i = 0; i < 8; i++)
                v[i] = yr[(size_t)idx[i] * 128 + lane];
#pragma unroll
            for (int i = 0; i < 8; i++)
                if (k0 + i < deg) acc += v[i];
        }
        float im = 1.0f / fmaxf((float)deg, 1.0f);
        float r = yr[(size_t)node * 128 + 64 + lane];
        float v = acc * im + r;
        float s = v * v;
#pragma unroll
        for (int m = 32; m >= 1; m >>= 1) s += __shfl_xor(s, m, 64);
        float rn = 1.0f / fmaxf(sqrtf(s), 1e-12f);
        out[(size_t)node * 64 + lane] = v * rn;
    }
}

extern "C" void kernel_launch(void* const* d_in, const int* in_sizes, int n_in,
                              void* d_out, int out_size, void* d_ws, size_t ws_size,
                              hipStream_t stream) {
    const float* x   = (const float*)d_in[0];
    const int*   ei  = (const int*)d_in[1];   // [2, E] int32
    const float* w1l = (const float*)d_in[2];
    const float* b1  = (const float*)d_in[3];
    const float* w1r = (const float*)d_in[4];
    const float* w2l = (const float*)d_in[5];
    const float* b2  = (const float*)d_in[6];
    const float* w2r = (const float*)d_in[7];
    float* out = (float*)d_out;

    const int* src = ei;
    const int* dst = ei + EE;

    char* ws = (char*)d_ws;
    auto align = [](size_t v) { return (v + 255) & ~(size_t)255; };
    int*   deg    = (int*)ws;                 size_t o = align((size_t)NN * 4);
    int*   rowoff = (int*)(ws + o);           o += align((size_t)(NN + 1) * 4);
    int*   cursor = (int*)(ws + o);           o += align((size_t)NN * 4);
    int*   csr    = (int*)(ws + o);           o += align((size_t)EE * 4);
    float* bufA   = (float*)(ws + o);         o += align((size_t)NN * 256 * 4);  // y|r layer1 (reused layer2)
    float* h1     = (float*)(ws + o);         // [NN][128]

    // ---- build CSR ----
    hipMemsetAsync(deg, 0, (size_t)NN * 4, stream);
    count_kernel<<<(EE + 255) / 256, 256, 0, stream>>>(dst, deg, EE);
    scan_kernel<<<1, 1024, 0, stream>>>(deg, rowoff, NN);
    cursor_init_kernel<<<(NN + 255) / 256, 256, 0, stream>>>(rowoff, cursor, NN);
    fill_kernel<<<(EE + 255) / 256, 256, 0, stream>>>(src, dst, cursor, csr, EE);

    // ---- layer 1: transform (y=x@W1l, r=x@W1r+b1) then gather+norm ----
    transform_kernel<256><<<(NN + 63) / 64, 256, 0, stream>>>(x, w1l, w1r, b1, bufA, NN);
    gather_norm_kernel<128><<<(NN + 3) / 4, 256, 0, stream>>>(bufA, rowoff, csr, h1, NN);

    // ---- layer 2 ----
    transform_kernel<128><<<(NN + 63) / 64, 256, 0, stream>>>(h1, w2l, w2r, b2, bufA, NN);
    gather_norm_kernel<64><<<(NN + 3) / 4, 256, 0, stream>>>(bufA, rowoff, csr, out, NN);
}

// Round 4
// 360.058 us; speedup vs baseline: 8.3655x; 1.1616x over previous
//
#include <hip/hip_runtime.h>
#include <math.h>

#define NN 50000
#define EE 800000
#define NB 196   // ceil(NN/256)

// ---------------- CSR build ----------------
__global__ void count_kernel(const int* __restrict__ dst, int* __restrict__ deg, int E) {
    int e = blockIdx.x * blockDim.x + threadIdx.x;
    if (e < E) atomicAdd(&deg[dst[e]], 1);
}

// phase 1: per-block sums of deg
__global__ void scan1_kernel(const int* __restrict__ deg, int* __restrict__ bsum, int n) {
    __shared__ int s[256];
    int t = threadIdx.x;
    int i = blockIdx.x * 256 + t;
    s[t] = (i < n) ? deg[i] : 0;
    __syncthreads();
    for (int ofs = 128; ofs > 0; ofs >>= 1) {
        if (t < ofs) s[t] += s[t + ofs];
        __syncthreads();
    }
    if (t == 0) bsum[blockIdx.x] = s[0];
}

// phase 2: exclusive scan of block sums (single small block)
__global__ void scan2_kernel(int* __restrict__ bsum, int nb) {
    __shared__ int s[256];
    int t = threadIdx.x;
    s[t] = (t < nb) ? bsum[t] : 0;
    __syncthreads();
    for (int ofs = 1; ofs < 256; ofs <<= 1) {
        int v = s[t];
        int a = (t >= ofs) ? s[t - ofs] : 0;
        __syncthreads();
        s[t] = v + a;
        __syncthreads();
    }
    if (t < nb) bsum[t] = (t == 0) ? 0 : s[t - 1];
}

// phase 3: in-block exclusive scan + block offset -> rowoff & cursor
__global__ void scan3_kernel(const int* __restrict__ deg, const int* __restrict__ bsum,
                             int* __restrict__ rowoff, int* __restrict__ cursor, int n) {
    __shared__ int s[256];
    int t = threadIdx.x;
    int i = blockIdx.x * 256 + t;
    int d = (i < n) ? deg[i] : 0;
    s[t] = d;
    __syncthreads();
    for (int ofs = 1; ofs < 256; ofs <<= 1) {
        int v = s[t];
        int a = (t >= ofs) ? s[t - ofs] : 0;
        __syncthreads();
        s[t] = v + a;
        __syncthreads();
    }
    int excl = s[t] - d + bsum[blockIdx.x];
    if (i < n) { rowoff[i] = excl; cursor[i] = excl; }
    if (i == n - 1) rowoff[n] = excl + d;
}

__global__ void fill_kernel(const int* __restrict__ src, const int* __restrict__ dst,
                            int* __restrict__ cursor, int* __restrict__ csr, int E) {
    int e = blockIdx.x * blockDim.x + threadIdx.x;
    if (e < E) {
        int d = dst[e];
        int p = atomicAdd(&cursor[d], 1);
        csr[p] = src[e];
    }
}

// ---------------- dense transform: out[n][CO] = x[n] @ [Wl | Wr], bias on right half ----
// K=128. CO=256 (layer1) or 128 (layer2). Wl,Wr row-major [K][CO/2].
template <int CO>
__global__ __launch_bounds__(256) void transform_kernel(
        const float* __restrict__ x, const float* __restrict__ wl,
        const float* __restrict__ wr, const float* __restrict__ bias,
        float* __restrict__ out, int n) {
    constexpr int K = 128;
    constexpr int NPB = 64;
    constexpr int CG = CO / 4;        // col groups of 4 cols
    constexpr int NG = 256 / CG;      // node groups
    constexpr int MY = NPB / NG;      // nodes per thread (16 or 8)
    constexpr int HALF = CO / 2;
    __shared__ float xs[NPB][K + 4];  // pad 4: conflict-light

    const int t = threadIdx.x;
    const int node0 = blockIdx.x * NPB;

    for (int e = t; e < NPB * 32; e += 256) {
        int c4 = e & 31, nd = e >> 5;
        int node = node0 + nd;
        float4 v = (node < n) ? ((const float4*)x)[(size_t)node * 32 + c4]
                              : make_float4(0.f, 0.f, 0.f, 0.f);
        *(float4*)&xs[nd][c4 * 4] = v;
    }
    __syncthreads();

    const int cg = t % CG;
    const int ng = t / CG;
    const int c0 = cg * 4;
    const bool right = (c0 >= HALF);
    const float* wsel = right ? wr : wl;
    const int cb = right ? (c0 - HALF) : c0;

    float acc[MY][4];
#pragma unroll
    for (int m = 0; m < MY; m++)
#pragma unroll
        for (int q = 0; q < 4; q++)
            acc[m][q] = right ? bias[cb + q] : 0.f;

    for (int k = 0; k < K; k++) {
        float4 w4 = *(const float4*)(wsel + (size_t)k * HALF + cb);
#pragma unroll
        for (int m = 0; m < MY; m++) {
            float xv = xs[ng * MY + m][k];   // whole-wave broadcast
            acc[m][0] += xv * w4.x;
            acc[m][1] += xv * w4.y;
            acc[m][2] += xv * w4.z;
            acc[m][3] += xv * w4.w;
        }
    }

#pragma unroll
    for (int m = 0; m < MY; m++) {
        int node = node0 + ng * MY + m;
        if (node < n)
            *(float4*)&out[(size_t)node * CO + c0] =
                make_float4(acc[m][0], acc[m][1], acc[m][2], acc[m][3]);
    }
}

// ---------------- gather + mean + add-root + L2norm ----------------
// yr rows: [y(0..D-1) | r(D..2D-1)], stride 2D. One wave per node.
template <int D>
__global__ __launch_bounds__(256) void gather_norm_kernel(
        const float* __restrict__ yr, const int* __restrict__ rowoff,
        const int* __restrict__ csr, float* __restrict__ out, int n) {
    const int wave = threadIdx.x >> 6;
    const int lane = threadIdx.x & 63;
    const int node = blockIdx.x * 4 + wave;
    if (node >= n) return;

    const int off = rowoff[node];
    const int end = rowoff[node + 1];
    const int deg = end - off;

    if (D == 128) {
        float2 acc = make_float2(0.f, 0.f);
        for (int k0 = 0; k0 < deg; k0 += 8) {
            int idx[8];
#pragma unroll
            for (int i = 0; i < 8; i++) {
                int kk = off + k0 + i;
                idx[i] = csr[kk < end ? kk : end - 1];
            }
            float2 v[8];
#pragma unroll
            for (int i = 0; i < 8; i++)
                v[i] = *(const float2*)(yr + (size_t)idx[i] * 256 + 2 * lane);
#pragma unroll
            for (int i = 0; i < 8; i++)
                if (k0 + i < deg) { acc.x += v[i].x; acc.y += v[i].y; }
        }
        float im = 1.0f / fmaxf((float)deg, 1.0f);
        float2 r = *(const float2*)(yr + (size_t)node * 256 + 128 + 2 * lane);
        float2 v = make_float2(acc.x * im + r.x, acc.y * im + r.y);
        float s = v.x * v.x + v.y * v.y;
#pragma unroll
        for (int m = 32; m >= 1; m >>= 1) s += __shfl_xor(s, m, 64);
        float rn = 1.0f / fmaxf(sqrtf(s), 1e-12f);
        *(float2*)&out[(size_t)node * 128 + 2 * lane] = make_float2(v.x * rn, v.y * rn);
    } else {
        float acc = 0.f;
        for (int k0 = 0; k0 < deg; k0 += 8) {
            int idx[8];
#pragma unroll
            for (int i = 0; i < 8; i++) {
                int kk = off + k0 + i;
                idx[i] = csr[kk < end ? kk : end - 1];
            }
            float v[8];
#pragma unroll
            for (int i = 0; i < 8; i++)
                v[i] = yr[(size_t)idx[i] * 128 + lane];
#pragma unroll
            for (int i = 0; i < 8; i++)
                if (k0 + i < deg) acc += v[i];
        }
        float im = 1.0f / fmaxf((float)deg, 1.0f);
        float r = yr[(size_t)node * 128 + 64 + lane];
        float v = acc * im + r;
        float s = v * v;
#pragma unroll
        for (int m = 32; m >= 1; m >>= 1) s += __shfl_xor(s, m, 64);
        float rn = 1.0f / fmaxf(sqrtf(s), 1e-12f);
        out[(size_t)node * 64 + lane] = v * rn;
    }
}

extern "C" void kernel_launch(void* const* d_in, const int* in_sizes, int n_in,
                              void* d_out, int out_size, void* d_ws, size_t ws_size,
                              hipStream_t stream) {
    const float* x   = (const float*)d_in[0];
    const int*   ei  = (const int*)d_in[1];   // [2, E] int32
    const float* w1l = (const float*)d_in[2];
    const float* b1  = (const float*)d_in[3];
    const float* w1r = (const float*)d_in[4];
    const float* w2l = (const float*)d_in[5];
    const float* b2  = (const float*)d_in[6];
    const float* w2r = (const float*)d_in[7];
    float* out = (float*)d_out;

    const int* src = ei;
    const int* dst = ei + EE;

    char* ws = (char*)d_ws;
    auto align = [](size_t v) { return (v + 255) & ~(size_t)255; };
    int*   deg    = (int*)ws;                 size_t o = align((size_t)NN * 4);
    int*   rowoff = (int*)(ws + o);           o += align((size_t)(NN + 1) * 4);
    int*   cursor = (int*)(ws + o);           o += align((size_t)NN * 4);
    int*   bsum   = (int*)(ws + o);           o += align((size_t)NB * 4);
    int*   csr    = (int*)(ws + o);           o += align((size_t)EE * 4);
    float* bufA   = (float*)(ws + o);         o += align((size_t)NN * 256 * 4);  // y|r
    float* h1     = (float*)(ws + o);         // [NN][128]

    // ---- build CSR (hierarchical scan) ----
    hipMemsetAsync(deg, 0, (size_t)NN * 4, stream);
    count_kernel<<<(EE + 255) / 256, 256, 0, stream>>>(dst, deg, EE);
    scan1_kernel<<<NB, 256, 0, stream>>>(deg, bsum, NN);
    scan2_kernel<<<1, 256, 0, stream>>>(bsum, NB);
    scan3_kernel<<<NB, 256, 0, stream>>>(deg, bsum, rowoff, cursor, NN);
    fill_kernel<<<(EE + 255) / 256, 256, 0, stream>>>(src, dst, cursor, csr, EE);

    // ---- layer 1: transform (y=x@W1l, r=x@W1r+b1) then gather+norm ----
    transform_kernel<256><<<(NN + 63) / 64, 256, 0, stream>>>(x, w1l, w1r, b1, bufA, NN);
    gather_norm_kernel<128><<<(NN + 3) / 4, 256, 0, stream>>>(bufA, rowoff, csr, h1, NN);

    // ---- layer 2 ----
    transform_kernel<128><<<(NN + 63) / 64, 256, 0, stream>>>(h1, w2l, w2r, b2, bufA, NN);
    gather_norm_kernel<64><<<(NN + 3) / 4, 256, 0, stream>>>(bufA, rowoff, csr, out, NN);
}

// Round 5
// 315.160 us; speedup vs baseline: 9.5572x; 1.1425x over previous
//
#include <hip/hip_runtime.h>
#include <math.h>

#define NN 50000
#define EE 800000
#define NB 196   // ceil(NN/256)

typedef __attribute__((ext_vector_type(8))) short bf16x8;
typedef __attribute__((ext_vector_type(16))) float f32x16;
typedef __attribute__((ext_vector_type(4))) unsigned short us4;

__device__ inline unsigned short bf16_rne(float f) {
    union { float f; unsigned u; } a; a.f = f;
    unsigned u = a.u;
    u += 0x7fff + ((u >> 16) & 1);
    return (unsigned short)(u >> 16);
}

// ---------------- CSR build ----------------
__global__ void count_kernel(const int* __restrict__ dst, int* __restrict__ deg, int E) {
    int e = blockIdx.x * blockDim.x + threadIdx.x;
    if (e < E) atomicAdd(&deg[dst[e]], 1);
}

__global__ void scan1_kernel(const int* __restrict__ deg, int* __restrict__ bsum, int n) {
    __shared__ int s[256];
    int t = threadIdx.x;
    int i = blockIdx.x * 256 + t;
    s[t] = (i < n) ? deg[i] : 0;
    __syncthreads();
    for (int ofs = 128; ofs > 0; ofs >>= 1) {
        if (t < ofs) s[t] += s[t + ofs];
        __syncthreads();
    }
    if (t == 0) bsum[blockIdx.x] = s[0];
}

__global__ void scan2_kernel(int* __restrict__ bsum, int nb) {
    __shared__ int s[256];
    int t = threadIdx.x;
    s[t] = (t < nb) ? bsum[t] : 0;
    __syncthreads();
    for (int ofs = 1; ofs < 256; ofs <<= 1) {
        int v = s[t];
        int a = (t >= ofs) ? s[t - ofs] : 0;
        __syncthreads();
        s[t] = v + a;
        __syncthreads();
    }
    if (t < nb) bsum[t] = (t == 0) ? 0 : s[t - 1];
}

__global__ void scan3_kernel(const int* __restrict__ deg, const int* __restrict__ bsum,
                             int* __restrict__ rowoff, int* __restrict__ cursor, int n) {
    __shared__ int s[256];
    int t = threadIdx.x;
    int i = blockIdx.x * 256 + t;
    int d = (i < n) ? deg[i] : 0;
    s[t] = d;
    __syncthreads();
    for (int ofs = 1; ofs < 256; ofs <<= 1) {
        int v = s[t];
        int a = (t >= ofs) ? s[t - ofs] : 0;
        __syncthreads();
        s[t] = v + a;
        __syncthreads();
    }
    int excl = s[t] - d + bsum[blockIdx.x];
    if (i < n) { rowoff[i] = excl; cursor[i] = excl; }
    if (i == n - 1) rowoff[n] = excl + d;
}

__global__ void fill_kernel(const int* __restrict__ src, const int* __restrict__ dst,
                            int* __restrict__ cursor, int* __restrict__ csr, int E) {
    int e = blockIdx.x * blockDim.x + threadIdx.x;
    if (e < E) {
        int d = dst[e];
        int p = atomicAdd(&cursor[d], 1);
        csr[p] = src[e];
    }
}

// ---------------- weight prep: wt[n][k] = bf16([Wl|Wr]^T), n in [0,2*HALF) ----------------
__global__ void prep_w_kernel(const float* __restrict__ wl, const float* __restrict__ wr,
                              unsigned short* __restrict__ wt, int HALF, int K) {
    int idx = blockIdx.x * 256 + threadIdx.x;
    int total = 2 * HALF * K;
    if (idx >= total) return;
    int n = idx / K, k = idx % K;
    float v = (n < HALF) ? wl[(size_t)k * HALF + n] : wr[(size_t)k * HALF + (n - HALF)];
    wt[idx] = bf16_rne(v);
}

// ---------------- MFMA transform: out[node][CO] = x[node] @ [Wl|Wr] (+bias on right) ----
// K=128. Block = 4 waves -> 64-node x 64-col tile. grid.y = CO/64.
template <int CO>
__global__ __launch_bounds__(256) void transform_mfma_kernel(
        const float* __restrict__ x, const unsigned short* __restrict__ wt,
        const float* __restrict__ bias, float* __restrict__ out, int n) {
    constexpr int HALF = CO / 2;
    constexpr int LDW = 136;   // 128 + 8 pad (272B row stride, 16B aligned)
    __shared__ unsigned short Xs[64][LDW];
    __shared__ unsigned short Ws[64][LDW];

    const int t = threadIdx.x;
    const int node0 = blockIdx.x * 64;
    const int gy = blockIdx.y;

    // stage X tile: 64 nodes x 128 k, fp32 -> bf16
    for (int e = t; e < 64 * 32; e += 256) {
        int nd = e >> 5, c4 = e & 31;
        int node = node0 + nd;
        float4 v = (node < n) ? ((const float4*)x)[(size_t)node * 32 + c4]
                              : make_float4(0.f, 0.f, 0.f, 0.f);
        us4 p;
        p.x = bf16_rne(v.x); p.y = bf16_rne(v.y); p.z = bf16_rne(v.z); p.w = bf16_rne(v.w);
        *(us4*)&Xs[nd][c4 * 4] = p;
    }
    // stage W tile: rows gy*64 .. +63, each 128 bf16
    for (int e = t; e < 64 * 16; e += 256) {
        int nd = e >> 4, c8 = e & 15;
        int4 v = ((const int4*)(wt + ((size_t)(gy * 64 + nd)) * 128))[c8];
        *(int4*)&Ws[nd][c8 * 8] = v;
    }
    __syncthreads();

    const int lane = t & 63, wave = t >> 6;
    const int wm = (wave & 1) * 32, wn = (wave >> 1) * 32;
    const int ml = wm + (lane & 31);
    const int nl = wn + (lane & 31);
    const int koff = (lane >> 5) * 8;

    f32x16 acc;
#pragma unroll
    for (int r = 0; r < 16; r++) acc[r] = 0.f;

#pragma unroll
    for (int kk = 0; kk < 8; kk++) {
        bf16x8 a = *(const bf16x8*)&Xs[ml][kk * 16 + koff];
        bf16x8 b = *(const bf16x8*)&Ws[nl][kk * 16 + koff];
        acc = __builtin_amdgcn_mfma_f32_32x32x16_bf16(a, b, acc, 0, 0, 0);
    }

#pragma unroll
    for (int r = 0; r < 16; r++) {
        int row = (r & 3) + 8 * (r >> 2) + 4 * (lane >> 5);
        int node = node0 + wm + row;
        int col = gy * 64 + wn + (lane & 31);
        if (node < n) {
            float v = acc[r];
            if (col >= HALF) v += bias[col - HALF];
            out[(size_t)node * CO + col] = v;
        }
    }
}

// ---------------- gather + mean + add-root + L2norm ----------------
// yr rows: [y(0..D-1) | r(D..2D-1)], stride 2D. One wave per node.
template <int D>
__global__ __launch_bounds__(256) void gather_norm_kernel(
        const float* __restrict__ yr, const int* __restrict__ rowoff,
        const int* __restrict__ csr, float* __restrict__ out, int n) {
    const int wave = threadIdx.x >> 6;
    const int lane = threadIdx.x & 63;
    const int node = blockIdx.x * 4 + wave;
    if (node >= n) return;

    const int off = rowoff[node];
    const int end = rowoff[node + 1];
    const int deg = end - off;

    if (D == 128) {
        float2 acc = make_float2(0.f, 0.f);
        for (int k0 = 0; k0 < deg; k0 += 8) {
            int idx[8];
#pragma unroll
            for (int i = 0; i < 8; i++) {
                int kk = off + k0 + i;
                idx[i] = csr[kk < end ? kk : end - 1];
            }
            float2 v[8];
#pragma unroll
            for (int i = 0; i < 8; i++)
                v[i] = *(const float2*)(yr + (size_t)idx[i] * 256 + 2 * lane);
#pragma unroll
            for (int i = 0; i < 8; i++)
                if (k0 + i < deg) { acc.x += v[i].x; acc.y += v[i].y; }
        }
        float im = 1.0f / fmaxf((float)deg, 1.0f);
        float2 r = *(const float2*)(yr + (size_t)node * 256 + 128 + 2 * lane);
        float2 v = make_float2(acc.x * im + r.x, acc.y * im + r.y);
        float s = v.x * v.x + v.y * v.y;
#pragma unroll
        for (int m = 32; m >= 1; m >>= 1) s += __shfl_xor(s, m, 64);
        float rn = 1.0f / fmaxf(sqrtf(s), 1e-12f);
        *(float2*)&out[(size_t)node * 128 + 2 * lane] = make_float2(v.x * rn, v.y * rn);
    } else {
        float acc = 0.f;
        for (int k0 = 0; k0 < deg; k0 += 8) {
            int idx[8];
#pragma unroll
            for (int i = 0; i < 8; i++) {
                int kk = off + k0 + i;
                idx[i] = csr[kk < end ? kk : end - 1];
            }
            float v[8];
#pragma unroll
            for (int i = 0; i < 8; i++)
                v[i] = yr[(size_t)idx[i] * 128 + lane];
#pragma unroll
            for (int i = 0; i < 8; i++)
                if (k0 + i < deg) acc += v[i];
        }
        float im = 1.0f / fmaxf((float)deg, 1.0f);
        float r = yr[(size_t)node * 128 + 64 + lane];
        float v = acc * im + r;
        float s = v * v;
#pragma unroll
        for (int m = 32; m >= 1; m >>= 1) s += __shfl_xor(s, m, 64);
        float rn = 1.0f / fmaxf(sqrtf(s), 1e-12f);
        out[(size_t)node * 64 + lane] = v * rn;
    }
}

extern "C" void kernel_launch(void* const* d_in, const int* in_sizes, int n_in,
                              void* d_out, int out_size, void* d_ws, size_t ws_size,
                              hipStream_t stream) {
    const float* x   = (const float*)d_in[0];
    const int*   ei  = (const int*)d_in[1];   // [2, E] int32
    const float* w1l = (const float*)d_in[2];
    const float* b1  = (const float*)d_in[3];
    const float* w1r = (const float*)d_in[4];
    const float* w2l = (const float*)d_in[5];
    const float* b2  = (const float*)d_in[6];
    const float* w2r = (const float*)d_in[7];
    float* out = (float*)d_out;

    const int* src = ei;
    const int* dst = ei + EE;

    char* ws = (char*)d_ws;
    auto align = [](size_t v) { return (v + 255) & ~(size_t)255; };
    int*   deg    = (int*)ws;                 size_t o = align((size_t)NN * 4);
    int*   rowoff = (int*)(ws + o);           o += align((size_t)(NN + 1) * 4);
    int*   cursor = (int*)(ws + o);           o += align((size_t)NN * 4);
    int*   bsum   = (int*)(ws + o);           o += align((size_t)NB * 4);
    int*   csr    = (int*)(ws + o);           o += align((size_t)EE * 4);
    unsigned short* wt1 = (unsigned short*)(ws + o); o += align((size_t)256 * 128 * 2);
    unsigned short* wt2 = (unsigned short*)(ws + o); o += align((size_t)128 * 128 * 2);
    float* bufA   = (float*)(ws + o);         o += align((size_t)NN * 256 * 4);  // y|r
    float* h1     = (float*)(ws + o);         // [NN][128]

    // ---- build CSR (hierarchical scan) ----
    hipMemsetAsync(deg, 0, (size_t)NN * 4, stream);
    count_kernel<<<(EE + 255) / 256, 256, 0, stream>>>(dst, deg, EE);
    scan1_kernel<<<NB, 256, 0, stream>>>(deg, bsum, NN);
    scan2_kernel<<<1, 256, 0, stream>>>(bsum, NB);
    scan3_kernel<<<NB, 256, 0, stream>>>(deg, bsum, rowoff, cursor, NN);
    fill_kernel<<<(EE + 255) / 256, 256, 0, stream>>>(src, dst, cursor, csr, EE);

    // ---- weight prep (bf16 transposed, [Wl|Wr] packed) ----
    prep_w_kernel<<<(256 * 128 + 255) / 256, 256, 0, stream>>>(w1l, w1r, wt1, 128, 128);
    prep_w_kernel<<<(128 * 128 + 255) / 256, 256, 0, stream>>>(w2l, w2r, wt2, 64, 128);

    // ---- layer 1: MFMA transform then gather+norm ----
    transform_mfma_kernel<256><<<dim3((NN + 63) / 64, 4), 256, 0, stream>>>(x, wt1, b1, bufA, NN);
    gather_norm_kernel<128><<<(NN + 3) / 4, 256, 0, stream>>>(bufA, rowoff, csr, h1, NN);

    // ---- layer 2 ----
    transform_mfma_kernel<128><<<dim3((NN + 63) / 64, 2), 256, 0, stream>>>(h1, wt2, b2, bufA, NN);
    gather_norm_kernel<64><<<(NN + 3) / 4, 256, 0, stream>>>(bufA, rowoff, csr, out, NN);
}

// Round 6
// 295.429 us; speedup vs baseline: 10.1955x; 1.0668x over previous
//
#include <hip/hip_runtime.h>
#include <math.h>

#define NN 50000
#define EE 800000
#define NB 196   // ceil(NN/256)

typedef __attribute__((ext_vector_type(8))) short bf16x8;
typedef __attribute__((ext_vector_type(16))) float f32x16;
typedef __attribute__((ext_vector_type(4))) unsigned short us4;

__device__ inline unsigned short bf16_rne(float f) {
    union { float f; unsigned u; } a; a.f = f;
    unsigned u = a.u;
    u += 0x7fff + ((u >> 16) & 1);
    return (unsigned short)(u >> 16);
}
__device__ inline float bf16_to_f32(unsigned short u) {
    union { unsigned u; float f; } a; a.u = ((unsigned)u) << 16;
    return a.f;
}

// ---------------- CSR build ----------------
__global__ void count_kernel(const int* __restrict__ dst, int* __restrict__ deg, int E) {
    int e = blockIdx.x * blockDim.x + threadIdx.x;
    if (e < E) atomicAdd(&deg[dst[e]], 1);
}

__global__ void scan1_kernel(const int* __restrict__ deg, int* __restrict__ bsum, int n) {
    __shared__ int s[256];
    int t = threadIdx.x;
    int i = blockIdx.x * 256 + t;
    s[t] = (i < n) ? deg[i] : 0;
    __syncthreads();
    for (int ofs = 128; ofs > 0; ofs >>= 1) {
        if (t < ofs) s[t] += s[t + ofs];
        __syncthreads();
    }
    if (t == 0) bsum[blockIdx.x] = s[0];
}

__global__ void scan2_kernel(int* __restrict__ bsum, int nb) {
    __shared__ int s[256];
    int t = threadIdx.x;
    s[t] = (t < nb) ? bsum[t] : 0;
    __syncthreads();
    for (int ofs = 1; ofs < 256; ofs <<= 1) {
        int v = s[t];
        int a = (t >= ofs) ? s[t - ofs] : 0;
        __syncthreads();
        s[t] = v + a;
        __syncthreads();
    }
    if (t < nb) bsum[t] = (t == 0) ? 0 : s[t - 1];
}

__global__ void scan3_kernel(const int* __restrict__ deg, const int* __restrict__ bsum,
                             int* __restrict__ rowoff, int* __restrict__ cursor, int n) {
    __shared__ int s[256];
    int t = threadIdx.x;
    int i = blockIdx.x * 256 + t;
    int d = (i < n) ? deg[i] : 0;
    s[t] = d;
    __syncthreads();
    for (int ofs = 1; ofs < 256; ofs <<= 1) {
        int v = s[t];
        int a = (t >= ofs) ? s[t - ofs] : 0;
        __syncthreads();
        s[t] = v + a;
        __syncthreads();
    }
    int excl = s[t] - d + bsum[blockIdx.x];
    if (i < n) { rowoff[i] = excl; cursor[i] = excl; }
    if (i == n - 1) rowoff[n] = excl + d;
}

__global__ void fill_kernel(const int* __restrict__ src, const int* __restrict__ dst,
                            int* __restrict__ cursor, int* __restrict__ csr, int E) {
    int e = blockIdx.x * blockDim.x + threadIdx.x;
    if (e < E) {
        int d = dst[e];
        int p = atomicAdd(&cursor[d], 1);
        csr[p] = src[e];
    }
}

// ---------------- weight prep: wt[n][k] = bf16([Wl|Wr]^T) ----------------
__global__ void prep_w_kernel(const float* __restrict__ wl, const float* __restrict__ wr,
                              unsigned short* __restrict__ wt, int HALF, int K) {
    int idx = blockIdx.x * 256 + threadIdx.x;
    int total = 2 * HALF * K;
    if (idx >= total) return;
    int n = idx / K, k = idx % K;
    float v = (n < HALF) ? wl[(size_t)k * HALF + n] : wr[(size_t)k * HALF + (n - HALF)];
    wt[idx] = bf16_rne(v);
}

// ---------------- MFMA transform ----------------
// out: ybuf[node][HALF] bf16 (cols<HALF), rbuf[node][HALF] fp32 (+bias).
// K=128. Block = 4 waves -> 64-node x 64-col tile. grid.y = CO/64.
// BF16IN: x rows are bf16[128]; else fp32[128].
template <int CO, bool BF16IN>
__global__ __launch_bounds__(256) void transform_mfma_kernel(
        const void* __restrict__ xin, const unsigned short* __restrict__ wt,
        const float* __restrict__ bias, unsigned short* __restrict__ ybuf,
        float* __restrict__ rbuf, int n) {
    constexpr int HALF = CO / 2;
    constexpr int LDW = 136;   // 128 + 8 pad (272B row stride, 16B aligned)
    __shared__ unsigned short Xs[64][LDW];
    __shared__ unsigned short Ws[64][LDW];

    const int t = threadIdx.x;
    const int node0 = blockIdx.x * 64;
    const int gy = blockIdx.y;

    if (BF16IN) {
        const unsigned short* xb = (const unsigned short*)xin;
        for (int e = t; e < 64 * 16; e += 256) {
            int nd = e >> 4, c8 = e & 15;
            int node = node0 + nd;
            int4 v = (node < n) ? ((const int4*)(xb + (size_t)node * 128))[c8]
                                : make_int4(0, 0, 0, 0);
            *(int4*)&Xs[nd][c8 * 8] = v;
        }
    } else {
        const float* xf = (const float*)xin;
        for (int e = t; e < 64 * 32; e += 256) {
            int nd = e >> 5, c4 = e & 31;
            int node = node0 + nd;
            float4 v = (node < n) ? ((const float4*)xf)[(size_t)node * 32 + c4]
                                  : make_float4(0.f, 0.f, 0.f, 0.f);
            us4 p;
            p.x = bf16_rne(v.x); p.y = bf16_rne(v.y); p.z = bf16_rne(v.z); p.w = bf16_rne(v.w);
            *(us4*)&Xs[nd][c4 * 4] = p;
        }
    }
    for (int e = t; e < 64 * 16; e += 256) {
        int nd = e >> 4, c8 = e & 15;
        int4 v = ((const int4*)(wt + ((size_t)(gy * 64 + nd)) * 128))[c8];
        *(int4*)&Ws[nd][c8 * 8] = v;
    }
    __syncthreads();

    const int lane = t & 63, wave = t >> 6;
    const int wm = (wave & 1) * 32, wn = (wave >> 1) * 32;
    const int ml = wm + (lane & 31);
    const int nl = wn + (lane & 31);
    const int koff = (lane >> 5) * 8;

    f32x16 acc;
#pragma unroll
    for (int r = 0; r < 16; r++) acc[r] = 0.f;

#pragma unroll
    for (int kk = 0; kk < 8; kk++) {
        bf16x8 a = *(const bf16x8*)&Xs[ml][kk * 16 + koff];
        bf16x8 b = *(const bf16x8*)&Ws[nl][kk * 16 + koff];
        acc = __builtin_amdgcn_mfma_f32_32x32x16_bf16(a, b, acc, 0, 0, 0);
    }

    const int col = gy * 64 + wn + (lane & 31);   // wave-uniform half selection
    if (col < HALF) {
#pragma unroll
        for (int r = 0; r < 16; r++) {
            int row = (r & 3) + 8 * (r >> 2) + 4 * (lane >> 5);
            int node = node0 + wm + row;
            if (node < n) ybuf[(size_t)node * HALF + col] = bf16_rne(acc[r]);
        }
    } else {
        const float bj = bias[col - HALF];
#pragma unroll
        for (int r = 0; r < 16; r++) {
            int row = (r & 3) + 8 * (r >> 2) + 4 * (lane >> 5);
            int node = node0 + wm + row;
            if (node < n) rbuf[(size_t)node * HALF + (col - HALF)] = acc[r] + bj;
        }
    }
}

// ---------------- gather + mean + add-root + L2norm, D=128 ----------------
// y: bf16[node][128]; rr: fp32[node][128]; out: bf16 (OUTBF16) or fp32.
template <bool OUTBF16>
__global__ __launch_bounds__(256) void gather128_kernel(
        const unsigned short* __restrict__ y, const float* __restrict__ rr,
        const int* __restrict__ rowoff, const int* __restrict__ csr,
        void* __restrict__ out, int n) {
    const int wave = threadIdx.x >> 6;
    const int lane = threadIdx.x & 63;
    const int node = blockIdx.x * 4 + wave;
    if (node >= n) return;

    const int off = rowoff[node];
    const int end = rowoff[node + 1];
    const int deg = end - off;

    float2 acc = make_float2(0.f, 0.f);
    for (int k0 = 0; k0 < deg; k0 += 8) {
        int idx[8];
#pragma unroll
        for (int i = 0; i < 8; i++) {
            int kk = off + k0 + i;
            idx[i] = csr[kk < end ? kk : end - 1];
        }
        unsigned v[8];
#pragma unroll
        for (int i = 0; i < 8; i++)
            v[i] = *(const unsigned*)(y + (size_t)idx[i] * 128 + 2 * lane);
#pragma unroll
        for (int i = 0; i < 8; i++)
            if (k0 + i < deg) {
                acc.x += bf16_to_f32((unsigned short)(v[i] & 0xffff));
                acc.y += bf16_to_f32((unsigned short)(v[i] >> 16));
            }
    }
    float im = 1.0f / fmaxf((float)deg, 1.0f);
    float2 rv = *(const float2*)(rr + (size_t)node * 128 + 2 * lane);
    float2 v = make_float2(acc.x * im + rv.x, acc.y * im + rv.y);
    float s = v.x * v.x + v.y * v.y;
#pragma unroll
    for (int m = 32; m >= 1; m >>= 1) s += __shfl_xor(s, m, 64);
    float rn = 1.0f / fmaxf(sqrtf(s), 1e-12f);
    v.x *= rn; v.y *= rn;
    if (OUTBF16) {
        unsigned pk = (unsigned)bf16_rne(v.x) | ((unsigned)bf16_rne(v.y) << 16);
        *(unsigned*)((unsigned short*)out + (size_t)node * 128 + 2 * lane) = pk;
    } else {
        *(float2*)((float*)out + (size_t)node * 128 + 2 * lane) = v;
    }
}

// ---------------- gather + mean + add-root + L2norm, D=64, fp32 out ----------------
__global__ __launch_bounds__(256) void gather64_kernel(
        const unsigned short* __restrict__ y, const float* __restrict__ rr,
        const int* __restrict__ rowoff, const int* __restrict__ csr,
        float* __restrict__ out, int n) {
    const int wave = threadIdx.x >> 6;
    const int lane = threadIdx.x & 63;
    const int node = blockIdx.x * 4 + wave;
    if (node >= n) return;

    const int off = rowoff[node];
    const int end = rowoff[node + 1];
    const int deg = end - off;

    float acc = 0.f;
    for (int k0 = 0; k0 < deg; k0 += 8) {
        int idx[8];
#pragma unroll
        for (int i = 0; i < 8; i++) {
            int kk = off + k0 + i;
            idx[i] = csr[kk < end ? kk : end - 1];
        }
        unsigned short v[8];
#pragma unroll
        for (int i = 0; i < 8; i++)
            v[i] = y[(size_t)idx[i] * 64 + lane];
#pragma unroll
        for (int i = 0; i < 8; i++)
            if (k0 + i < deg) acc += bf16_to_f32(v[i]);
    }
    float im = 1.0f / fmaxf((float)deg, 1.0f);
    float r = rr[(size_t)node * 64 + lane];
    float v = acc * im + r;
    float s = v * v;
#pragma unroll
    for (int m = 32; m >= 1; m >>= 1) s += __shfl_xor(s, m, 64);
    float rn = 1.0f / fmaxf(sqrtf(s), 1e-12f);
    out[(size_t)node * 64 + lane] = v * rn;
}

extern "C" void kernel_launch(void* const* d_in, const int* in_sizes, int n_in,
                              void* d_out, int out_size, void* d_ws, size_t ws_size,
                              hipStream_t stream) {
    const float* x   = (const float*)d_in[0];
    const int*   ei  = (const int*)d_in[1];   // [2, E] int32
    const float* w1l = (const float*)d_in[2];
    const float* b1  = (const float*)d_in[3];
    const float* w1r = (const float*)d_in[4];
    const float* w2l = (const float*)d_in[5];
    const float* b2  = (const float*)d_in[6];
    const float* w2r = (const float*)d_in[7];
    float* out = (float*)d_out;

    const int* src = ei;
    const int* dst = ei + EE;

    char* ws = (char*)d_ws;
    auto align = [](size_t v) { return (v + 255) & ~(size_t)255; };
    int*   deg    = (int*)ws;                 size_t o = align((size_t)NN * 4);
    int*   rowoff = (int*)(ws + o);           o += align((size_t)(NN + 1) * 4);
    int*   cursor = (int*)(ws + o);           o += align((size_t)NN * 4);
    int*   bsum   = (int*)(ws + o);           o += align((size_t)NB * 4);
    int*   csr    = (int*)(ws + o);           o += align((size_t)EE * 4);
    unsigned short* wt1 = (unsigned short*)(ws + o); o += align((size_t)256 * 128 * 2);
    unsigned short* wt2 = (unsigned short*)(ws + o); o += align((size_t)128 * 128 * 2);
    unsigned short* y1  = (unsigned short*)(ws + o); o += align((size_t)NN * 128 * 2); // bf16
    float*          r1  = (float*)(ws + o);          o += align((size_t)NN * 128 * 4);
    unsigned short* h1  = (unsigned short*)(ws + o); o += align((size_t)NN * 128 * 2); // bf16
    unsigned short* y2  = (unsigned short*)(ws + o); o += align((size_t)NN * 64 * 2);  // bf16
    float*          r2  = (float*)(ws + o);          o += align((size_t)NN * 64 * 4);

    // ---- build CSR (hierarchical scan) ----
    hipMemsetAsync(deg, 0, (size_t)NN * 4, stream);
    count_kernel<<<(EE + 255) / 256, 256, 0, stream>>>(dst, deg, EE);
    scan1_kernel<<<NB, 256, 0, stream>>>(deg, bsum, NN);
    scan2_kernel<<<1, 256, 0, stream>>>(bsum, NB);
    scan3_kernel<<<NB, 256, 0, stream>>>(deg, bsum, rowoff, cursor, NN);
    fill_kernel<<<(EE + 255) / 256, 256, 0, stream>>>(src, dst, cursor, csr, EE);

    // ---- weight prep (bf16 transposed, [Wl|Wr] packed) ----
    prep_w_kernel<<<(256 * 128 + 255) / 256, 256, 0, stream>>>(w1l, w1r, wt1, 128, 128);
    prep_w_kernel<<<(128 * 128 + 255) / 256, 256, 0, stream>>>(w2l, w2r, wt2, 64, 128);

    // ---- layer 1: MFMA transform (y1 bf16, r1 fp32) then gather+norm -> h1 bf16 ----
    transform_mfma_kernel<256, false><<<dim3((NN + 63) / 64, 4), 256, 0, stream>>>(
        x, wt1, b1, y1, r1, NN);
    gather128_kernel<true><<<(NN + 3) / 4, 256, 0, stream>>>(y1, r1, rowoff, csr, h1, NN);

    // ---- layer 2: bf16-input transform then gather+norm -> out fp32 ----
    transform_mfma_kernel<128, true><<<dim3((NN + 63) / 64, 2), 256, 0, stream>>>(
        h1, wt2, b2, y2, r2, NN);
    gather64_kernel<<<(NN + 3) / 4, 256, 0, stream>>>(y2, r2, rowoff, csr, out, NN);
}